// Round 3
// baseline (694.308 us; speedup 1.0000x reference)
//
#include <hip/hip_runtime.h>
#include <math.h>

// SwitchMOE: B=8,T=2048,D=1024,F=4096,E=16 ; capacity=1280, K=13
// R7: resubmit of R6 (infra failure, not kernel). E1/E2/expand = R4-measured
// best (664.8us). Router: stage Wr into LDS in TWO 32KB halves (3 barriers
// total vs R4's 32 per block), barrier-free accumulate loops, 512 blocks.
// 33KB static LDS (safely under any 64KB static cap), 3-4 blocks/CU.

#define TOKENS 16384
#define DD     1024
#define FF     4096
#define EE     16
#define CAP    1280
#define KMAX   13
#define NBLK   512   // router/hist blocks, 32 tokens each

// ---------------------------------------------------------------- router ----
// 512 blocks x 256 thr; 32 tokens/block, 8 per wave (2 groups of 4).
// Wr staged in two 32KB halves (experts 0-7, then 8-15); inner accumulate
// loops are barrier-free; x rows held in registers across both halves.
__global__ __launch_bounds__(256) void router_kernel(
    const float* __restrict__ x, const float* __restrict__ Wr,
    int* __restrict__ top1, float* __restrict__ top1p,
    int* __restrict__ blockhist, float* __restrict__ blockpsum)
{
    __shared__ float wr_l[8 * DD];    // 32 KB: one half of Wr
    __shared__ float p_acc[EE];
    __shared__ int   hist[EE];

    const int tid  = threadIdx.x;
    const int wave = tid >> 6;
    const int lane = tid & 63;
    const int blk  = blockIdx.x;

    if (tid < EE) { p_acc[tid] = 0.0f; hist[tid] = 0; }

    // x rows for both token groups held in registers for the whole kernel:
    // 8 tokens/wave * 4 float4 = 32 float4 regs... too many; keep per-group.
    float acc[2][4][EE];   // [group][token][expert]
    float4 xr[2][4][4];    // [group][token][j]

    #pragma unroll
    for (int it = 0; it < 2; ++it) {
        const int tbase = blk * 32 + wave * 8 + it * 4;
        #pragma unroll
        for (int t = 0; t < 4; ++t) {
            const float4* xp = (const float4*)(x + (size_t)(tbase + t) * DD);
            #pragma unroll
            for (int j = 0; j < 4; ++j) xr[it][t][j] = xp[j * 64 + lane];
        }
        #pragma unroll
        for (int t = 0; t < 4; ++t)
            #pragma unroll
            for (int e = 0; e < EE; ++e) acc[it][t][e] = 0.0f;
    }

    #pragma unroll
    for (int half = 0; half < 2; ++half) {
        if (half) __syncthreads();    // protect readers of previous half
        // stage 8 experts: 2048 float4, 8 per thread, coalesced
        #pragma unroll
        for (int i = 0; i < 8; ++i)
            ((float4*)wr_l)[i * 256 + tid] =
                ((const float4*)Wr)[half * 2048 + i * 256 + tid];
        __syncthreads();

        #pragma unroll
        for (int j = 0; j < 4; ++j) {
            #pragma unroll
            for (int eh = 0; eh < 8; ++eh) {
                const int e = half * 8 + eh;
                const float4 w = ((const float4*)(wr_l + eh * DD))[j * 64 + lane];
                #pragma unroll
                for (int it = 0; it < 2; ++it) {
                    acc[it][0][e] += xr[it][0][j].x*w.x + xr[it][0][j].y*w.y + xr[it][0][j].z*w.z + xr[it][0][j].w*w.w;
                    acc[it][1][e] += xr[it][1][j].x*w.x + xr[it][1][j].y*w.y + xr[it][1][j].z*w.z + xr[it][1][j].w*w.w;
                    acc[it][2][e] += xr[it][2][j].x*w.x + xr[it][2][j].y*w.y + xr[it][2][j].z*w.z + xr[it][2][j].w*w.w;
                    acc[it][3][e] += xr[it][3][j].x*w.x + xr[it][3][j].y*w.y + xr[it][3][j].z*w.z + xr[it][3][j].w*w.w;
                }
            }
        }
    }

    #pragma unroll
    for (int it = 0; it < 2; ++it) {
        const int tbase = blk * 32 + wave * 8 + it * 4;

        // butterfly reduce: every lane ends with all totals
        #pragma unroll
        for (int t = 0; t < 4; ++t)
            #pragma unroll
            for (int e = 0; e < EE; ++e) {
                float v = acc[it][t][e];
                v += __shfl_xor(v, 32);
                v += __shfl_xor(v, 16);
                v += __shfl_xor(v, 8);
                v += __shfl_xor(v, 4);
                v += __shfl_xor(v, 2);
                v += __shfl_xor(v, 1);
                acc[it][t][e] = v;
            }

        if (lane < 4) {
            float lg[EE];
            #pragma unroll
            for (int e = 0; e < EE; ++e) {
                float v = acc[it][3][e];
                if (lane == 2) v = acc[it][2][e];
                if (lane == 1) v = acc[it][1][e];
                if (lane == 0) v = acc[it][0][e];
                lg[e] = v;
            }
            const int gt = tbase + lane;
            float mx = lg[0]; int bi = 0;
            #pragma unroll
            for (int e = 1; e < EE; ++e)
                if (lg[e] > mx) { mx = lg[e]; bi = e; }   // first-max like argmax
            float pr[EE];
            float s = 0.0f;
            #pragma unroll
            for (int e = 0; e < EE; ++e) { pr[e] = expf(lg[e] - mx); s += pr[e]; }
            const float inv = 1.0f / s;
            top1[gt]  = bi;
            top1p[gt] = inv;                 // = exp(0)/s = max prob
            #pragma unroll
            for (int e = 0; e < EE; ++e) atomicAdd(&p_acc[e], pr[e] * inv);
            atomicAdd(&hist[bi], 1);
        }
    }
    __syncthreads();
    if (tid < EE) {
        blockhist[blk * EE + tid] = hist[tid];
        blockpsum[blk * EE + tid] = p_acc[tid];
    }
}

// ------------------------------------------------------------------ scan ----
// single block: exclusive prefix of blockhist over 512 blocks per expert,
// n_kept, token-0 fill multiplicity, lb_loss (reducing blockpsum).
__global__ __launch_bounds__(256) void scan_kernel(
    const int* __restrict__ blockhist, const float* __restrict__ blockpsum,
    int* __restrict__ base, int* __restrict__ nkept,
    const int* __restrict__ top1, float* __restrict__ mult0,
    float* __restrict__ lb_out)
{
    __shared__ int   hist_l[NBLK * EE];   // 32 KB
    __shared__ int   gsum[EE * 16];
    __shared__ float fps[EE * 16];
    __shared__ float fp[EE];
    __shared__ int   nk_l[EE];

    const int tid = threadIdx.x;
    for (int i = tid; i < NBLK * EE; i += 256) hist_l[i] = blockhist[i];
    __syncthreads();

    const int e = tid >> 4, g = tid & 15;   // 16 experts x 16 groups of 32 blocks
    int s = 0;
    float sp = 0.0f;
    for (int b = g * 32; b < g * 32 + 32; ++b) {
        s  += hist_l[b * EE + e];
        sp += blockpsum[b * EE + e];
    }
    gsum[e * 16 + g] = s;
    fps[e * 16 + g]  = sp;
    __syncthreads();

    int pre = 0;
    for (int g2 = 0; g2 < g; ++g2) pre += gsum[e * 16 + g2];
    int run = pre;
    for (int b = g * 32; b < g * 32 + 32; ++b) {
        base[b * EE + e] = run;
        run += hist_l[b * EE + e];
    }
    if (g == 15) {
        const int c = run;                      // total count for expert e
        const int nk = (c > 0) ? ((c - 1) / CAP + 1) : 0;
        nkept[e] = nk;
        nk_l[e]  = nk;
        float ps = 0.0f;
        for (int g2 = 0; g2 < 16; ++g2) ps += fps[e * 16 + g2];
        fp[e] = ((float)c / (float)TOKENS) * (ps / (float)TOKENS);
    }
    __syncthreads();
    if (tid == 0) {
        const int e0 = top1[0];
        mult0[0] = (float)(1 + KMAX - nk_l[e0]);  // token-0 fill multiplicity
        float sum = 0.0f;
        for (int i = 0; i < EE; ++i) sum += fp[i];
        lb_out[0] = (float)EE * sum * 0.01f;
    }
}

// ------------------------------------------------------------------ keep ----
// per 64-token block: within-32-token-subblock rank recount -> kept-slot list
// + full slotmap write (hist blocks are 32 tokens).
__global__ __launch_bounds__(64) void keep_kernel(
    const int* __restrict__ top1, const float* __restrict__ top1p,
    const int* __restrict__ base, const float* __restrict__ mult0,
    int* __restrict__ kept_tok, float* __restrict__ kept_scale,
    int* __restrict__ slotmap)
{
    __shared__ int t1[64];
    const int tid = threadIdx.x;
    const int blk = blockIdx.x;
    const int gt  = blk * 64 + tid;
    const int e   = top1[gt];
    t1[tid] = e;
    __syncthreads();
    const int start = tid & 32;               // 32-token sub-block boundary
    int r = 0;
    for (int i = start; i < tid; ++i) r += (t1[i] == e) ? 1 : 0;
    const int hb   = gt >> 5;                 // 32-token hist block index
    const int rank = base[hb * EE + e] + r;
    int sm = -1;
    if (rank % CAP == 0) {
        const int slot = rank / CAP;          // kth kept token has rank k*CAP
        sm = e * KMAX + slot;
        kept_tok[sm] = gt;
        float sc = top1p[gt];
        if (gt == 0) sc *= mult0[0];          // fold fill-slot multiplicity
        kept_scale[sm] = sc;
    }
    slotmap[gt] = sm;
}

// ------------------------------------------------------------------- E1 -----
// h[e][s][f] = gelu(W1[e,f,:] . x[t_s] + b1[e,f]).
// grid EE*256, wave handles 4 f-rows; x re-read per row (L1-hot: same 4KB
// row for all 4 waves of the block) -> low VGPR, 8 waves/SIMD, compiler free
// to pipeline row i+1's loads over row i's reduce.  [R4-measured-best]
__global__ __launch_bounds__(256) void expert1_kernel(
    const float* __restrict__ x, const float* __restrict__ W1,
    const float* __restrict__ b1, const int* __restrict__ nkept,
    const int* __restrict__ kept_tok, float* __restrict__ h)
{
    const int e    = blockIdx.x >> 8;
    const int fblk = blockIdx.x & 255;
    const int ne   = nkept[e];
    if (ne == 0) return;
    const int wave = threadIdx.x >> 6;
    const int lane = threadIdx.x & 63;

    for (int s = 0; s < ne; ++s) {
        const int t = kept_tok[e * KMAX + s];
        const float4* xp = (const float4*)(x + (size_t)t * DD);
        #pragma unroll
        for (int i = 0; i < 4; ++i) {
            const int f = fblk * 16 + wave * 4 + i;
            const float4* wrow = (const float4*)(W1 + ((size_t)e * FF + f) * DD);
            float d = 0.0f;
            #pragma unroll
            for (int k = 0; k < 4; ++k) {
                const float4 w  = wrow[k * 64 + lane];
                const float4 xv = xp[k * 64 + lane];
                d += w.x*xv.x + w.y*xv.y + w.z*xv.z + w.w*xv.w;
            }
            d += __shfl_xor(d, 32);
            d += __shfl_xor(d, 16);
            d += __shfl_xor(d, 8);
            d += __shfl_xor(d, 4);
            d += __shfl_xor(d, 2);
            d += __shfl_xor(d, 1);
            if (lane == 0) {
                const float v = d + b1[e * FF + f];
                // exact gelu: 0.5*v*(1+erf(v/sqrt(2)))
                h[((size_t)e * KMAX + s) * FF + f] =
                    0.5f * v * (1.0f + erff(v * 0.70710678118654752440f));
            }
        }
    }
}

// ------------------------------------------------------------------- E2 -----
// eo[e][s][d] = scale * (W2[e,d,:] . h[e][s][:] + b2[e,d]).
// grid EE*256 (8 blocks/CU co-resident), wave-per-d-row: 16 w (HBM) + 16 h
// (L2-hot, h totals 256KB) float4 loads in flight, ONE butterfly per 16KB.
// No LDS, no barriers -> nothing drains the load queue.  [R4-measured-best]
__global__ __launch_bounds__(256) void expert2_kernel(
    const float* __restrict__ h, const float* __restrict__ W2,
    const float* __restrict__ b2, const int* __restrict__ nkept,
    const float* __restrict__ kept_scale, float* __restrict__ eo)
{
    const int e    = blockIdx.x >> 8;
    const int dblk = blockIdx.x & 255;
    const int ne   = nkept[e];
    if (ne == 0) return;
    const int wave = threadIdx.x >> 6;
    const int lane = threadIdx.x & 63;
    const int d    = dblk * 4 + wave;

    const float4* wrow = (const float4*)(W2 + ((size_t)e * DD + d) * FF);
    for (int s = 0; s < ne; ++s) {
        const float4* hp = (const float4*)(h + ((size_t)e * KMAX + s) * FF);
        float acc = 0.0f;
        #pragma unroll
        for (int k = 0; k < 16; ++k) {
            const float4 w  = wrow[k * 64 + lane];
            const float4 hv = hp[k * 64 + lane];
            acc += w.x*hv.x + w.y*hv.y + w.z*hv.z + w.w*hv.w;
        }
        acc += __shfl_xor(acc, 32);
        acc += __shfl_xor(acc, 16);
        acc += __shfl_xor(acc, 8);
        acc += __shfl_xor(acc, 4);
        acc += __shfl_xor(acc, 2);
        acc += __shfl_xor(acc, 1);
        if (lane == 0) {
            const float sc = kept_scale[e * KMAX + s];
            eo[((size_t)e * KMAX + s) * DD + d] = sc * (acc + b2[e * DD + d]);
        }
    }
}

// ---------------------------------------------------------------- expand ----
// single coalesced pass writing the full output (zeros or scattered eo rows;
// scale+bias already folded into eo by E2).
__global__ __launch_bounds__(256) void expand_kernel(
    const float* __restrict__ eo, const int* __restrict__ slotmap,
    float* __restrict__ out)
{
    const int nf4 = TOKENS * DD / 4;            // 4194304 float4
    int idx = blockIdx.x * 256 + threadIdx.x;
    const int stride = 4096 * 256;
    for (; idx < nf4; idx += stride) {
        const int t    = idx >> 8;              // 256 float4 per token
        const int slot = slotmap[t];
        float4 v = make_float4(0.0f, 0.0f, 0.0f, 0.0f);
        if (slot >= 0) v = ((const float4*)eo)[slot * 256 + (idx & 255)];
        ((float4*)out)[idx] = v;
    }
}

// -------------------------------------------------------------- launcher ----
extern "C" void kernel_launch(void* const* d_in, const int* in_sizes, int n_in,
                              void* d_out, int out_size, void* d_ws, size_t ws_size,
                              hipStream_t stream) {
    const float* x  = (const float*)d_in[0];
    const float* Wr = (const float*)d_in[1];
    const float* W1 = (const float*)d_in[2];
    const float* b1 = (const float*)d_in[3];
    const float* W2 = (const float*)d_in[4];
    const float* b2 = (const float*)d_in[5];
    float* out = (float*)d_out;

    char* p = (char*)d_ws;
    int*   top1       = (int*)p;    p += (size_t)TOKENS * 4;
    float* top1p      = (float*)p;  p += (size_t)TOKENS * 4;
    int*   slotmap    = (int*)p;    p += (size_t)TOKENS * 4;
    int*   blockhist  = (int*)p;    p += (size_t)NBLK * EE * 4;
    float* blockpsum  = (float*)p;  p += (size_t)NBLK * EE * 4;
    int*   base       = (int*)p;    p += (size_t)NBLK * EE * 4;
    int*   nkept      = (int*)p;    p += 256;
    float* mult0      = (float*)p;  p += 256;
    int*   kept_tok   = (int*)p;    p += 1024;   // EE*KMAX ints, padded
    float* kept_scale = (float*)p;  p += 1024;
    float* eo         = (float*)p;  p += (size_t)EE * KMAX * DD * 4;
    float* h          = (float*)p;  p += (size_t)EE * KMAX * FF * 4;
    (void)ws_size; (void)in_sizes; (void)n_in;

    router_kernel<<<NBLK, 256, 0, stream>>>(x, Wr, top1, top1p,
                                            blockhist, blockpsum);
    scan_kernel<<<1, 256, 0, stream>>>(blockhist, blockpsum, base, nkept,
                                       top1, mult0, out + (size_t)out_size - 1);
    keep_kernel<<<256, 64, 0, stream>>>(top1, top1p, base, mult0,
                                        kept_tok, kept_scale, slotmap);
    expert1_kernel<<<EE * 256, 256, 0, stream>>>(x, W1, b1, nkept, kept_tok, h);
    expert2_kernel<<<EE * 256, 256, 0, stream>>>(h, W2, b2, nkept, kept_scale, eo);
    expand_kernel<<<4096, 256, 0, stream>>>(eo, slotmap, out);
}